// Round 1
// baseline (503.967 us; speedup 1.0000x reference)
//
#include <hip/hip_runtime.h>
#include <stdint.h>

// Problem constants (hard-coded: B=4, S=2048, D=1024, H=16, dk=64)
#define D_MODEL 1024
#define SEQ     2048
#define BATCH   4
#define NH      16
#define DKK     64
#define MROWS   (BATCH * SEQ)   // 8192

typedef unsigned short u16;
using bf16x8 = __attribute__((ext_vector_type(8))) __bf16;
using f32x4  = __attribute__((ext_vector_type(4))) float;

// float -> bf16 (RNE), bit-level so we don't depend on hip_bf16 header versioning
__device__ __forceinline__ u16 f2bf(float f) {
    union { float f; uint32_t u; } v; v.f = f;
    return (u16)((v.u + 0x7FFFu + ((v.u >> 16) & 1u)) >> 16);
}

// async global->LDS, 16B per lane; LDS dest must be wave-uniform base (+lane*16 implicit)
__device__ __forceinline__ void gl_lds16(const u16* g, u16* l) {
    __builtin_amdgcn_global_load_lds(
        (__attribute__((address_space(1))) void*)(const_cast<u16*>(g)),
        (__attribute__((address_space(3))) void*)l, 16, 0, 0);
}

// ---------------- fp32 -> bf16 convert (vectorized x4) ----------------
__global__ __launch_bounds__(256) void cvt_kernel(const float* __restrict__ src,
                                                  u16* __restrict__ dst, int n4) {
    int i = blockIdx.x * 256 + threadIdx.x;
    if (i >= n4) return;
    float4 v = ((const float4*)src)[i];
    ushort4 o;
    o.x = f2bf(v.x); o.y = f2bf(v.y); o.z = f2bf(v.z); o.w = f2bf(v.w);
    ((ushort4*)dst)[i] = o;
}

// ---------------- GEMM: C[M,N] = A[M,K] * B[N,K]^T, bf16 in, fp32 acc ----------------
// MODE 0: bf16 out row-major [M][N]
// MODE 1: bf16 out scattered to Vt[(b*NH+h)*DKK+d][s]  (V projection, pre-transposed heads)
// MODE 2: fp32 out row-major + bias (final projection)
template <int MODE>
__global__ __launch_bounds__(256, 2) void gemm_bt(const u16* __restrict__ A,
                                                  const u16* __restrict__ Bw,
                                                  u16* __restrict__ outb,
                                                  float* __restrict__ outf,
                                                  const float* __restrict__ bias) {
    constexpr int K = 1024, N = 1024;
    __shared__ u16 ldsA[128 * 32];
    __shared__ u16 ldsB[128 * 32];

    const int t = threadIdx.x;
    const int w = t >> 6, lane = t & 63;
    const int quad = lane >> 4, l15 = lane & 15;
    const int bn = blockIdx.x & 7, bm = blockIdx.x >> 3;
    const int wm = (w >> 1) * 64, wn = (w & 1) * 64;

    const u16* Ab = A  + (size_t)bm * 128 * K;
    const u16* Bb = Bw + (size_t)bn * 128 * K;
    const int srow  = lane >> 2;        // 0..15 within 16-row chunk
    const int scol8 = (lane & 3) * 8;   // k-offset 0/8/16/24

    f32x4 acc[4][4];
    #pragma unroll
    for (int i = 0; i < 4; ++i)
        #pragma unroll
        for (int j = 0; j < 4; ++j)
            acc[i][j] = f32x4{0.f, 0.f, 0.f, 0.f};

    for (int k0 = 0; k0 < K; k0 += 32) {
        __syncthreads();   // protect LDS from previous iteration's readers
        #pragma unroll
        for (int i = 0; i < 2; ++i) {
            const int c = w * 2 + i;   // chunk = 16 rows of 32 k (1KB)
            gl_lds16(Ab + (size_t)(c * 16 + srow) * K + k0 + scol8, &ldsA[c * 512]);
            gl_lds16(Bb + (size_t)(c * 16 + srow) * K + k0 + scol8, &ldsB[c * 512]);
        }
        __syncthreads();   // compiler drains vmcnt before s_barrier

        bf16x8 afr[4], bfr[4];
        #pragma unroll
        for (int i = 0; i < 4; ++i)
            afr[i] = *(const bf16x8*)&ldsA[(wm + i * 16 + l15) * 32 + quad * 8];
        #pragma unroll
        for (int j = 0; j < 4; ++j)
            bfr[j] = *(const bf16x8*)&ldsB[(wn + j * 16 + l15) * 32 + quad * 8];

        #pragma unroll
        for (int i = 0; i < 4; ++i)
            #pragma unroll
            for (int j = 0; j < 4; ++j)
                acc[i][j] = __builtin_amdgcn_mfma_f32_16x16x32_bf16(afr[i], bfr[j], acc[i][j], 0, 0, 0);
    }

    // epilogue: C/D layout col=lane&15, row=quad*4+reg (m89-verified)
    #pragma unroll
    for (int i = 0; i < 4; ++i) {
        #pragma unroll
        for (int j = 0; j < 4; ++j) {
            #pragma unroll
            for (int r = 0; r < 4; ++r) {
                const int row = bm * 128 + wm + i * 16 + quad * 4 + r;
                const int col = bn * 128 + wn + j * 16 + l15;
                const float v = acc[i][j][r];
                if constexpr (MODE == 0) {
                    outb[(size_t)row * N + col] = f2bf(v);
                } else if constexpr (MODE == 1) {
                    const int bb = row >> 11, ss = row & 2047;   // S = 2048
                    const int hh = col >> 6,  dd = col & 63;     // dk = 64
                    outb[(size_t)((bb * NH + hh) * DKK + dd) * SEQ + ss] = f2bf(v);
                } else {
                    outf[(size_t)row * N + col] = v + bias[col];
                }
            }
        }
    }
}

// ---------------- causal flash attention ----------------
// Grid: B*H*(S/64) blocks. Block = 4 waves; wave w owns q rows [q0+16w, q0+16w+16).
// Qb,Kb: [B*S][1024] bf16 (head h at cols h*64..). Vt: [(b*NH+h)*64+d][S] bf16.
__global__ __launch_bounds__(256, 2) void flash_attn(const u16* __restrict__ Qb,
                                                     const u16* __restrict__ Kb,
                                                     const u16* __restrict__ Vt,
                                                     u16* __restrict__ O) {
    __shared__ u16 ldsK[2][64 * 32];      // chunk d0: [s-row 0..63][32 d] (64B rows)
    __shared__ u16 ldsV[2][64 * 32];      // chunk s0: [d-row 0..63][32 s]
    __shared__ u16 ldsP[4][2][16 * 32];   // per-wave P, chunk ks: [m 0..15][32 k]

    const int t = threadIdx.x;
    const int w = t >> 6, lane = t & 63;
    const int quad = lane >> 4, l15 = lane & 15;
    const int qt = blockIdx.x & 31;
    const int h  = (blockIdx.x >> 5) & 15;
    const int b  = blockIdx.x >> 9;
    const int q0 = qt * 64;
    const int qw = q0 + w * 16;           // wave's first q row

    // Q fragments (A layout: m=lane&15, k=quad*8+j), loaded once
    const u16* Qrow = Qb + (size_t)(b * SEQ + qw + l15) * D_MODEL + h * DKK;
    const bf16x8 qf0 = *(const bf16x8*)(Qrow + quad * 8);
    const bf16x8 qf1 = *(const bf16x8*)(Qrow + 32 + quad * 8);

    f32x4 o_acc[4];
    #pragma unroll
    for (int nt = 0; nt < 4; ++nt) o_acc[nt] = f32x4{0.f, 0.f, 0.f, 0.f};
    float m_i[4], l_i[4];
    #pragma unroll
    for (int r = 0; r < 4; ++r) { m_i[r] = -1e30f; l_i[r] = 0.f; }

    const int srow  = lane >> 2;
    const int scol8 = (lane & 3) * 8;

    for (int it = 0; it <= qt; ++it) {
        const int kb = it * 64;
        __syncthreads();
        #pragma unroll
        for (int i = 0; i < 2; ++i) {
            const int e = w * 2 + i, ch = e >> 2, rb = (e & 3) * 16;
            gl_lds16(Kb + (size_t)(b * SEQ + kb + rb + srow) * D_MODEL + h * DKK + ch * 32 + scol8,
                     &ldsK[ch][rb * 32]);
            gl_lds16(Vt + (size_t)((b * NH + h) * DKK + rb + srow) * SEQ + kb + ch * 32 + scol8,
                     &ldsV[ch][rb * 32]);
        }
        __syncthreads();

        // S = Q K^T
        f32x4 sc[4];
        #pragma unroll
        for (int jt = 0; jt < 4; ++jt) sc[jt] = f32x4{0.f, 0.f, 0.f, 0.f};
        #pragma unroll
        for (int ks = 0; ks < 2; ++ks) {
            const bf16x8 qf = ks ? qf1 : qf0;
            #pragma unroll
            for (int jt = 0; jt < 4; ++jt) {
                bf16x8 kf = *(const bf16x8*)&ldsK[ks][(jt * 16 + l15) * 32 + quad * 8];
                sc[jt] = __builtin_amdgcn_mfma_f32_16x16x32_bf16(qf, kf, sc[jt], 0, 0, 0);
            }
        }

        // scale 1/sqrt(dk) + causal mask
        const bool needmask = (kb + 63 > qw);   // wave-uniform
        #pragma unroll
        for (int jt = 0; jt < 4; ++jt)
            #pragma unroll
            for (int r = 0; r < 4; ++r) {
                float v = sc[jt][r] * 0.125f;
                if (needmask) {
                    const int qg = qw + quad * 4 + r;
                    const int kg = kb + jt * 16 + l15;
                    if (kg > qg) v = -1e30f;
                }
                sc[jt][r] = v;
            }

        // row max across 16 lanes of the quad (row = quad*4+reg lives in one quad)
        float tmax[4];
        #pragma unroll
        for (int r = 0; r < 4; ++r)
            tmax[r] = fmaxf(fmaxf(sc[0][r], sc[1][r]), fmaxf(sc[2][r], sc[3][r]));
        #pragma unroll
        for (int off = 1; off < 16; off <<= 1)
            #pragma unroll
            for (int r = 0; r < 4; ++r)
                tmax[r] = fmaxf(tmax[r], __shfl_xor(tmax[r], off));

        float alpha[4];
        #pragma unroll
        for (int r = 0; r < 4; ++r) {
            const float mn = fmaxf(m_i[r], tmax[r]);
            alpha[r] = __expf(m_i[r] - mn);
            m_i[r] = mn;
        }

        // P = exp(S - m), row sums
        float tsum[4] = {0.f, 0.f, 0.f, 0.f};
        #pragma unroll
        for (int jt = 0; jt < 4; ++jt)
            #pragma unroll
            for (int r = 0; r < 4; ++r) {
                const float p = __expf(sc[jt][r] - m_i[r]);
                sc[jt][r] = p;
                tsum[r] += p;
            }
        #pragma unroll
        for (int off = 1; off < 16; off <<= 1)
            #pragma unroll
            for (int r = 0; r < 4; ++r)
                tsum[r] += __shfl_xor(tsum[r], off);
        #pragma unroll
        for (int r = 0; r < 4; ++r) l_i[r] = l_i[r] * alpha[r] + tsum[r];
        #pragma unroll
        for (int nt = 0; nt < 4; ++nt)
            #pragma unroll
            for (int r = 0; r < 4; ++r)
                o_acc[nt][r] *= alpha[r];

        // P: C layout -> A layout via per-wave LDS round-trip (m120 method)
        #pragma unroll
        for (int jt = 0; jt < 4; ++jt)
            #pragma unroll
            for (int r = 0; r < 4; ++r)
                ldsP[w][jt >> 1][(quad * 4 + r) * 32 + (jt & 1) * 16 + l15] = f2bf(sc[jt][r]);
        asm volatile("s_waitcnt lgkmcnt(0)" ::: "memory");

        // O += P V
        #pragma unroll
        for (int ks = 0; ks < 2; ++ks) {
            bf16x8 pf = *(const bf16x8*)&ldsP[w][ks][l15 * 32 + quad * 8];
            #pragma unroll
            for (int nt = 0; nt < 4; ++nt) {
                bf16x8 vf = *(const bf16x8*)&ldsV[ks][(nt * 16 + l15) * 32 + quad * 8];
                o_acc[nt] = __builtin_amdgcn_mfma_f32_16x16x32_bf16(pf, vf, o_acc[nt], 0, 0, 0);
            }
        }
    }

    // epilogue: O[b, q, h*64+d] bf16
    #pragma unroll
    for (int nt = 0; nt < 4; ++nt)
        #pragma unroll
        for (int r = 0; r < 4; ++r) {
            const float val = o_acc[nt][r] / l_i[r];
            const int qg = qw + quad * 4 + r;
            O[(size_t)(b * SEQ + qg) * D_MODEL + h * DKK + nt * 16 + l15] = f2bf(val);
        }
}

// ---------------- host launch ----------------
extern "C" void kernel_launch(void* const* d_in, const int* in_sizes, int n_in,
                              void* d_out, int out_size, void* d_ws, size_t ws_size,
                              hipStream_t stream) {
    const float* q_in = (const float*)d_in[0];
    const float* k_in = (const float*)d_in[1];
    const float* v_in = (const float*)d_in[2];
    const float* Wq   = (const float*)d_in[3];
    const float* Wk   = (const float*)d_in[4];
    const float* Wv   = (const float*)d_in[5];
    const float* Wp   = (const float*)d_in[6];
    const float* bp   = (const float*)d_in[7];
    float* out = (float*)d_out;

    char* ws = (char*)d_ws;
    u16* XQ  = (u16*)(ws + (size_t)0);          // 16MB; reused as AttnOut after Q-GEMM
    u16* XK  = (u16*)(ws + ((size_t)16 << 20));
    u16* XV  = (u16*)(ws + ((size_t)32 << 20));
    u16* WQb = (u16*)(ws + ((size_t)48 << 20));
    u16* WKb = (u16*)(ws + ((size_t)50 << 20));
    u16* WVb = (u16*)(ws + ((size_t)52 << 20));
    u16* WPb = (u16*)(ws + ((size_t)54 << 20));
    u16* Qb  = (u16*)(ws + ((size_t)56 << 20));
    u16* Kb  = (u16*)(ws + ((size_t)72 << 20));
    u16* Vtb = (u16*)(ws + ((size_t)88 << 20));  // total footprint: 104 MB

    const int nbig = MROWS * D_MODEL;     // 8,388,608
    const int nw   = D_MODEL * D_MODEL;   // 1,048,576

    cvt_kernel<<<nbig / 1024, 256, 0, stream>>>(q_in, XQ, nbig / 4);
    cvt_kernel<<<nbig / 1024, 256, 0, stream>>>(k_in, XK, nbig / 4);
    cvt_kernel<<<nbig / 1024, 256, 0, stream>>>(v_in, XV, nbig / 4);
    cvt_kernel<<<nw / 1024, 256, 0, stream>>>(Wq, WQb, nw / 4);
    cvt_kernel<<<nw / 1024, 256, 0, stream>>>(Wk, WKb, nw / 4);
    cvt_kernel<<<nw / 1024, 256, 0, stream>>>(Wv, WVb, nw / 4);
    cvt_kernel<<<nw / 1024, 256, 0, stream>>>(Wp, WPb, nw / 4);

    gemm_bt<0><<<512, 256, 0, stream>>>(XQ, WQb, Qb, nullptr, nullptr);
    gemm_bt<0><<<512, 256, 0, stream>>>(XK, WKb, Kb, nullptr, nullptr);
    gemm_bt<1><<<512, 256, 0, stream>>>(XV, WVb, Vtb, nullptr, nullptr);

    flash_attn<<<BATCH * NH * (SEQ / 64), 256, 0, stream>>>(Qb, Kb, Vtb, XQ);

    gemm_bt<2><<<512, 256, 0, stream>>>(XQ, WPb, nullptr, out, bp);
}

// Round 2
// 372.738 us; speedup vs baseline: 1.3521x; 1.3521x over previous
//
#include <hip/hip_runtime.h>
#include <stdint.h>

// Problem constants (hard-coded: B=4, S=2048, D=1024, H=16, dk=64)
#define D_MODEL 1024
#define SEQ     2048
#define BATCH   4
#define NH      16
#define DKK     64
#define MROWS   (BATCH * SEQ)   // 8192

typedef unsigned short u16;
using bf16x8 = __attribute__((ext_vector_type(8))) __bf16;
using f32x4  = __attribute__((ext_vector_type(4))) float;

// float -> bf16 (RNE)
__device__ __forceinline__ u16 f2bf(float f) {
    union { float f; uint32_t u; } v; v.f = f;
    return (u16)((v.u + 0x7FFFu + ((v.u >> 16) & 1u)) >> 16);
}

__device__ __forceinline__ float fast_exp2(float x) {
    float r; asm("v_exp_f32 %0, %1" : "=v"(r) : "v"(x)); return r;
}
__device__ __forceinline__ float fast_rcp(float x) {
    float r; asm("v_rcp_f32 %0, %1" : "=v"(r) : "v"(x)); return r;
}

// async global->LDS, 16B per lane; LDS dest wave-uniform base (+lane*16 implicit)
__device__ __forceinline__ void gl_lds16(const u16* g, u16* l) {
    __builtin_amdgcn_global_load_lds(
        (__attribute__((address_space(1))) void*)(const_cast<u16*>(g)),
        (__attribute__((address_space(3))) void*)l, 16, 0, 0);
}

// ---------------- fused fp32 -> bf16 converts ----------------
__global__ __launch_bounds__(256) void cvt3_kernel(const float* __restrict__ a,
                                                   const float* __restrict__ b,
                                                   const float* __restrict__ c,
                                                   u16* __restrict__ da,
                                                   u16* __restrict__ db,
                                                   u16* __restrict__ dc) {
    const int i = blockIdx.x * 256 + threadIdx.x;       // 3 * 2^21 float4
    const int sel = i >> 21, off = i & ((1 << 21) - 1);
    const float* s = (sel == 0) ? a : (sel == 1) ? b : c;
    u16* d = (sel == 0) ? da : (sel == 1) ? db : dc;
    float4 v = ((const float4*)s)[off];
    ushort4 o;
    o.x = f2bf(v.x); o.y = f2bf(v.y); o.z = f2bf(v.z); o.w = f2bf(v.w);
    ((ushort4*)d)[off] = o;
}

__global__ __launch_bounds__(256) void cvt4_kernel(const float* __restrict__ a,
                                                   const float* __restrict__ b,
                                                   const float* __restrict__ c,
                                                   const float* __restrict__ d4,
                                                   u16* __restrict__ da,
                                                   u16* __restrict__ db,
                                                   u16* __restrict__ dc,
                                                   u16* __restrict__ dd) {
    const int i = blockIdx.x * 256 + threadIdx.x;       // 4 * 2^18 float4
    const int sel = i >> 18, off = i & ((1 << 18) - 1);
    const float* s = (sel == 0) ? a : (sel == 1) ? b : (sel == 2) ? c : d4;
    u16* d = (sel == 0) ? da : (sel == 1) ? db : (sel == 2) ? dc : dd;
    float4 v = ((const float4*)s)[off];
    ushort4 o;
    o.x = f2bf(v.x); o.y = f2bf(v.y); o.z = f2bf(v.z); o.w = f2bf(v.w);
    ((ushort4*)d)[off] = o;
}

// ---------------- fused QKV GEMM: C[M,1024] = A[M,1024] * W[1024,1024]^T ----------------
// which=0/1: bf16 row-major (Q/K). which=2: Vt[(b*NH+h)*DKK+d][s] scatter.
__global__ __launch_bounds__(256, 2) void gemm_qkv(const u16* __restrict__ XQ,
                                                   const u16* __restrict__ XK,
                                                   const u16* __restrict__ XV,
                                                   const u16* __restrict__ WQ,
                                                   const u16* __restrict__ WK,
                                                   const u16* __restrict__ WV,
                                                   u16* __restrict__ Qo,
                                                   u16* __restrict__ Ko,
                                                   u16* __restrict__ Vto) {
    constexpr int K = 1024, N = 1024;
    __shared__ u16 ldsA[128 * 32];
    __shared__ u16 ldsB[128 * 32];

    const int which = blockIdx.x >> 9;       // 512 blocks per matmul
    const int inner = blockIdx.x & 511;
    const u16* A  = (which == 0) ? XQ : (which == 1) ? XK : XV;
    const u16* Bw = (which == 0) ? WQ : (which == 1) ? WK : WV;

    const int t = threadIdx.x;
    const int w = t >> 6, lane = t & 63;
    const int quad = lane >> 4, l15 = lane & 15;
    const int bn = inner & 7, bm = inner >> 3;
    const int wm = (w >> 1) * 64, wn = (w & 1) * 64;

    const u16* Ab = A  + (size_t)bm * 128 * K;
    const u16* Bb = Bw + (size_t)bn * 128 * K;
    const int srow  = lane >> 2;
    const int scol8 = (lane & 3) * 8;

    f32x4 acc[4][4];
    #pragma unroll
    for (int i = 0; i < 4; ++i)
        #pragma unroll
        for (int j = 0; j < 4; ++j)
            acc[i][j] = f32x4{0.f, 0.f, 0.f, 0.f};

    for (int k0 = 0; k0 < K; k0 += 32) {
        __syncthreads();
        #pragma unroll
        for (int i = 0; i < 2; ++i) {
            const int c = w * 2 + i;
            gl_lds16(Ab + (size_t)(c * 16 + srow) * K + k0 + scol8, &ldsA[c * 512]);
            gl_lds16(Bb + (size_t)(c * 16 + srow) * K + k0 + scol8, &ldsB[c * 512]);
        }
        __syncthreads();

        bf16x8 afr[4], bfr[4];
        #pragma unroll
        for (int i = 0; i < 4; ++i)
            afr[i] = *(const bf16x8*)&ldsA[(wm + i * 16 + l15) * 32 + quad * 8];
        #pragma unroll
        for (int j = 0; j < 4; ++j)
            bfr[j] = *(const bf16x8*)&ldsB[(wn + j * 16 + l15) * 32 + quad * 8];

        #pragma unroll
        for (int i = 0; i < 4; ++i)
            #pragma unroll
            for (int j = 0; j < 4; ++j)
                acc[i][j] = __builtin_amdgcn_mfma_f32_16x16x32_bf16(afr[i], bfr[j], acc[i][j], 0, 0, 0);
    }

    if (which < 2) {
        u16* outb = which ? Ko : Qo;
        #pragma unroll
        for (int i = 0; i < 4; ++i)
            #pragma unroll
            for (int j = 0; j < 4; ++j)
                #pragma unroll
                for (int r = 0; r < 4; ++r) {
                    const int row = bm * 128 + wm + i * 16 + quad * 4 + r;
                    const int col = bn * 128 + wn + j * 16 + l15;
                    outb[(size_t)row * N + col] = f2bf(acc[i][j][r]);
                }
    } else {
        #pragma unroll
        for (int i = 0; i < 4; ++i)
            #pragma unroll
            for (int j = 0; j < 4; ++j)
                #pragma unroll
                for (int r = 0; r < 4; ++r) {
                    const int row = bm * 128 + wm + i * 16 + quad * 4 + r;
                    const int col = bn * 128 + wn + j * 16 + l15;
                    const int bb = row >> 11, ss = row & 2047;
                    const int hh = col >> 6,  dd = col & 63;
                    Vto[(size_t)((bb * NH + hh) * DKK + dd) * SEQ + ss] = f2bf(acc[i][j][r]);
                }
    }
}

// ---------------- final projection GEMM: out[M,N] fp32 = A*W^T + bias ----------------
__global__ __launch_bounds__(256, 2) void gemm_proj(const u16* __restrict__ A,
                                                    const u16* __restrict__ Bw,
                                                    float* __restrict__ outf,
                                                    const float* __restrict__ bias) {
    constexpr int K = 1024, N = 1024;
    __shared__ u16 ldsA[128 * 32];
    __shared__ u16 ldsB[128 * 32];

    const int t = threadIdx.x;
    const int w = t >> 6, lane = t & 63;
    const int quad = lane >> 4, l15 = lane & 15;
    const int bn = blockIdx.x & 7, bm = blockIdx.x >> 3;
    const int wm = (w >> 1) * 64, wn = (w & 1) * 64;

    const u16* Ab = A  + (size_t)bm * 128 * K;
    const u16* Bb = Bw + (size_t)bn * 128 * K;
    const int srow  = lane >> 2;
    const int scol8 = (lane & 3) * 8;

    f32x4 acc[4][4];
    #pragma unroll
    for (int i = 0; i < 4; ++i)
        #pragma unroll
        for (int j = 0; j < 4; ++j)
            acc[i][j] = f32x4{0.f, 0.f, 0.f, 0.f};

    for (int k0 = 0; k0 < K; k0 += 32) {
        __syncthreads();
        #pragma unroll
        for (int i = 0; i < 2; ++i) {
            const int c = w * 2 + i;
            gl_lds16(Ab + (size_t)(c * 16 + srow) * K + k0 + scol8, &ldsA[c * 512]);
            gl_lds16(Bb + (size_t)(c * 16 + srow) * K + k0 + scol8, &ldsB[c * 512]);
        }
        __syncthreads();

        bf16x8 afr[4], bfr[4];
        #pragma unroll
        for (int i = 0; i < 4; ++i)
            afr[i] = *(const bf16x8*)&ldsA[(wm + i * 16 + l15) * 32 + quad * 8];
        #pragma unroll
        for (int j = 0; j < 4; ++j)
            bfr[j] = *(const bf16x8*)&ldsB[(wn + j * 16 + l15) * 32 + quad * 8];

        #pragma unroll
        for (int i = 0; i < 4; ++i)
            #pragma unroll
            for (int j = 0; j < 4; ++j)
                acc[i][j] = __builtin_amdgcn_mfma_f32_16x16x32_bf16(afr[i], bfr[j], acc[i][j], 0, 0, 0);
    }

    #pragma unroll
    for (int i = 0; i < 4; ++i)
        #pragma unroll
        for (int j = 0; j < 4; ++j)
            #pragma unroll
            for (int r = 0; r < 4; ++r) {
                const int row = bm * 128 + wm + i * 16 + quad * 4 + r;
                const int col = bn * 128 + wn + j * 16 + l15;
                outf[(size_t)row * N + col] = acc[i][j][r] + bias[col];
            }
}

// ---------------- causal flash attention v2 ----------------
// Grid: 2048 blocks; bh = idx & 63 (XCD locality: same bh -> same XCD via %8
// round-robin), qt = idx >> 6 (all concurrent blocks share qt -> balanced).
// Double-buffered K/V staging, ONE barrier per K-tile (prefetch issued after
// the barrier so its vmcnt drain lands behind the compute phase).
__global__ __launch_bounds__(256, 4) void flash_attn(const u16* __restrict__ Qb,
                                                     const u16* __restrict__ Kb,
                                                     const u16* __restrict__ Vt,
                                                     u16* __restrict__ O) {
    __shared__ u16 ldsK[2 * 4096];   // [buf][d-chunk(2)][s 0..63][32 d]  16KB
    __shared__ u16 ldsV[2 * 4096];   // [buf][s-chunk(2)][d 0..63][32 s]  16KB
    __shared__ u16 ldsP[4 * 1024];   // per-wave P [16 q][64 k], XOR-swizzled  8KB

    const int t = threadIdx.x;
    const int w = t >> 6, lane = t & 63;
    const int quad = lane >> 4, l15 = lane & 15;
    const int bh = blockIdx.x & 63;
    const int qt = blockIdx.x >> 6;
    const int b = bh >> 4, h = bh & 15;
    const int q0 = qt * 64;
    const int qw = q0 + w * 16;

    const int srow  = lane >> 2;
    const int scol8 = (lane & 3) * 8;
    const size_t kbase = (size_t)b * SEQ * D_MODEL + h * DKK;   // + row*D_MODEL
    const size_t vbase = (size_t)(bh * DKK) * SEQ;              // + d*SEQ + s

    // Q fragments (A layout: m=l15, k=quad*8+j)
    const u16* Qrow = Qb + (size_t)(b * SEQ + qw + l15) * D_MODEL + h * DKK;
    const bf16x8 qf0 = *(const bf16x8*)(Qrow + quad * 8);
    const bf16x8 qf1 = *(const bf16x8*)(Qrow + 32 + quad * 8);

    // ones B-fragment: B[0][k] = 1 -> row sums of P via MFMA
    bf16x8 onesf;
    {
        union { bf16x8 v; u16 s[8]; } uu;
        const u16 ov = (l15 == 0) ? (u16)0x3F80 : (u16)0;
        #pragma unroll
        for (int j = 0; j < 8; ++j) uu.s[j] = ov;
        onesf = uu.v;
    }

    f32x4 o_acc[4];
    #pragma unroll
    for (int nt = 0; nt < 4; ++nt) o_acc[nt] = f32x4{0.f, 0.f, 0.f, 0.f};
    float m_i[4], l_i[4];
    #pragma unroll
    for (int r = 0; r < 4; ++r) { m_i[r] = -1e30f; l_i[r] = 0.f; }

    const float C2 = 0.18033688f;   // log2(e) / sqrt(dk)

    // stage tile 0 into buffer 0
    {
        #pragma unroll
        for (int i = 0; i < 2; ++i) {
            const int e = w * 2 + i, ch = e >> 2, rb = (e & 3) * 16;
            gl_lds16(Kb + kbase + (size_t)(0 + rb + srow) * D_MODEL + ch * 32 + scol8,
                     &ldsK[ch * 2048 + rb * 32]);
            gl_lds16(Vt + vbase + (size_t)(rb + srow) * SEQ + 0 + ch * 32 + scol8,
                     &ldsV[ch * 2048 + rb * 32]);
        }
    }

    int cur = 0;
    for (int it = 0; it <= qt; ++it) {
        const int kb = it * 64;
        __syncthreads();   // drains vmcnt -> buf[cur] staged; prefetch below gets a full compute phase

        if (it < qt) {
            const int nb = (it + 1) * 64, nxt = cur ^ 1;
            #pragma unroll
            for (int i = 0; i < 2; ++i) {
                const int e = w * 2 + i, ch = e >> 2, rb = (e & 3) * 16;
                gl_lds16(Kb + kbase + (size_t)(nb + rb + srow) * D_MODEL + ch * 32 + scol8,
                         &ldsK[nxt * 4096 + ch * 2048 + rb * 32]);
                gl_lds16(Vt + vbase + (size_t)(rb + srow) * SEQ + nb + ch * 32 + scol8,
                         &ldsV[nxt * 4096 + ch * 2048 + rb * 32]);
            }
        }

        // ---- S = Q K^T ----
        f32x4 sc[4];
        #pragma unroll
        for (int jt = 0; jt < 4; ++jt) sc[jt] = f32x4{0.f, 0.f, 0.f, 0.f};
        #pragma unroll
        for (int ks = 0; ks < 2; ++ks) {
            const bf16x8 qf = ks ? qf1 : qf0;
            #pragma unroll
            for (int jt = 0; jt < 4; ++jt) {
                bf16x8 kf = *(const bf16x8*)&ldsK[cur * 4096 + ks * 2048 + (jt * 16 + l15) * 32 + quad * 8];
                sc[jt] = __builtin_amdgcn_mfma_f32_16x16x32_bf16(qf, kf, sc[jt], 0, 0, 0);
            }
        }

        // ---- causal mask (diag tile only, wave-uniform branch) ----
        if (kb + 63 > qw) {
            #pragma unroll
            for (int jt = 0; jt < 4; ++jt)
                #pragma unroll
                for (int r = 0; r < 4; ++r)
                    if (kb + jt * 16 + l15 > qw + quad * 4 + r) sc[jt][r] = -3.0e38f;
        }

        // ---- row max over the 16 lanes of the quad ----
        float tmax[4];
        #pragma unroll
        for (int r = 0; r < 4; ++r)
            tmax[r] = fmaxf(fmaxf(sc[0][r], sc[1][r]), fmaxf(sc[2][r], sc[3][r]));
        #pragma unroll
        for (int off = 1; off < 16; off <<= 1)
            #pragma unroll
            for (int r = 0; r < 4; ++r)
                tmax[r] = fmaxf(tmax[r], __shfl_xor(tmax[r], off));

        float alpha[4];
        #pragma unroll
        for (int r = 0; r < 4; ++r) {
            const float mn = fmaxf(m_i[r], tmax[r] * C2);
            alpha[r] = fast_exp2(m_i[r] - mn);
            m_i[r] = mn;
        }

        // ---- P = exp2(s*C2 - m), store C->A layout (XOR-swizzled granules) ----
        #pragma unroll
        for (int jt = 0; jt < 4; ++jt) {
            const int g = (jt * 2 + (l15 >> 3)) ^ quad;
            #pragma unroll
            for (int r = 0; r < 4; ++r) {
                const float p = fast_exp2(fmaf(sc[jt][r], C2, -m_i[r]));
                ldsP[w * 1024 + (quad * 4 + r) * 64 + g * 8 + (l15 & 7)] = f2bf(p);
            }
        }

        // rescale o while the P writes land
        #pragma unroll
        for (int nt = 0; nt < 4; ++nt)
            #pragma unroll
            for (int r = 0; r < 4; ++r)
                o_acc[nt][r] *= alpha[r];

        asm volatile("s_waitcnt lgkmcnt(0)" ::: "memory");

        // ---- O += P V ; row sums via MFMA with ones column ----
        f32x4 lacc = f32x4{0.f, 0.f, 0.f, 0.f};
        #pragma unroll
        for (int ks = 0; ks < 2; ++ks) {
            const int gg = (ks * 4 + quad) ^ (l15 >> 2);
            bf16x8 pf = *(const bf16x8*)&ldsP[w * 1024 + l15 * 64 + gg * 8];
            lacc = __builtin_amdgcn_mfma_f32_16x16x32_bf16(pf, onesf, lacc, 0, 0, 0);
            #pragma unroll
            for (int nt = 0; nt < 4; ++nt) {
                bf16x8 vf = *(const bf16x8*)&ldsV[cur * 4096 + ks * 2048 + (nt * 16 + l15) * 32 + quad * 8];
                o_acc[nt] = __builtin_amdgcn_mfma_f32_16x16x32_bf16(pf, vf, o_acc[nt], 0, 0, 0);
            }
        }

        #pragma unroll
        for (int r = 0; r < 4; ++r) {
            const float ts = __shfl(lacc[r], (lane & 48));   // col 0 lives in l15==0
            l_i[r] = fmaf(l_i[r], alpha[r], ts);
        }

        cur ^= 1;
    }

    // epilogue
    float rl[4];
    #pragma unroll
    for (int r = 0; r < 4; ++r) rl[r] = fast_rcp(l_i[r]);
    #pragma unroll
    for (int nt = 0; nt < 4; ++nt)
        #pragma unroll
        for (int r = 0; r < 4; ++r) {
            const int qg = qw + quad * 4 + r;
            O[(size_t)(b * SEQ + qg) * D_MODEL + h * DKK + nt * 16 + l15] = f2bf(o_acc[nt][r] * rl[r]);
        }
}

// ---------------- host launch ----------------
extern "C" void kernel_launch(void* const* d_in, const int* in_sizes, int n_in,
                              void* d_out, int out_size, void* d_ws, size_t ws_size,
                              hipStream_t stream) {
    const float* q_in = (const float*)d_in[0];
    const float* k_in = (const float*)d_in[1];
    const float* v_in = (const float*)d_in[2];
    const float* Wq   = (const float*)d_in[3];
    const float* Wk   = (const float*)d_in[4];
    const float* Wv   = (const float*)d_in[5];
    const float* Wp   = (const float*)d_in[6];
    const float* bp   = (const float*)d_in[7];
    float* out = (float*)d_out;

    char* ws = (char*)d_ws;
    u16* XQ  = (u16*)(ws + (size_t)0);           // 16MB; reused as AttnOut
    u16* XK  = (u16*)(ws + ((size_t)16 << 20));
    u16* XV  = (u16*)(ws + ((size_t)32 << 20));
    u16* WQb = (u16*)(ws + ((size_t)48 << 20));
    u16* WKb = (u16*)(ws + ((size_t)50 << 20));
    u16* WVb = (u16*)(ws + ((size_t)52 << 20));
    u16* WPb = (u16*)(ws + ((size_t)54 << 20));
    u16* Qb  = (u16*)(ws + ((size_t)56 << 20));
    u16* Kb  = (u16*)(ws + ((size_t)72 << 20));
    u16* Vtb = (u16*)(ws + ((size_t)88 << 20));  // total 104 MB

    // converts: 3 big activations (3*2^21 float4), 4 weights (4*2^18 float4)
    cvt3_kernel<<<3 * (1 << 21) / 256, 256, 0, stream>>>(q_in, k_in, v_in, XQ, XK, XV);
    cvt4_kernel<<<4 * (1 << 18) / 256, 256, 0, stream>>>(Wq, Wk, Wv, Wp, WQb, WKb, WVb, WPb);

    gemm_qkv<<<1536, 256, 0, stream>>>(XQ, XK, XV, WQb, WKb, WVb, Qb, Kb, Vtb);

    flash_attn<<<BATCH * NH * (SEQ / 64), 256, 0, stream>>>(Qb, Kb, Vtb, XQ);

    gemm_proj<<<512, 256, 0, stream>>>(XQ, WPb, out, bp);
}

// Round 3
// 347.816 us; speedup vs baseline: 1.4489x; 1.0717x over previous
//
#include <hip/hip_runtime.h>
#include <stdint.h>

// Problem constants (hard-coded: B=4, S=2048, D=1024, H=16, dk=64)
#define D_MODEL 1024
#define SEQ     2048
#define BATCH   4
#define NH      16
#define DKK     64
#define MROWS   (BATCH * SEQ)   // 8192

typedef unsigned short u16;
using bf16x8 = __attribute__((ext_vector_type(8))) __bf16;
using f32x4  = __attribute__((ext_vector_type(4))) float;

// float -> bf16 (RNE)
__device__ __forceinline__ u16 f2bf(float f) {
    union { float f; uint32_t u; } v; v.f = f;
    return (u16)((v.u + 0x7FFFu + ((v.u >> 16) & 1u)) >> 16);
}

__device__ __forceinline__ float fast_exp2(float x) {
    float r; asm("v_exp_f32 %0, %1" : "=v"(r) : "v"(x)); return r;
}
__device__ __forceinline__ float fast_rcp(float x) {
    float r; asm("v_rcp_f32 %0, %1" : "=v"(r) : "v"(x)); return r;
}

// async global->LDS, 16B per lane; LDS dest wave-uniform base (+lane*16 implicit)
__device__ __forceinline__ void gl_lds16(const u16* g, u16* l) {
    __builtin_amdgcn_global_load_lds(
        (__attribute__((address_space(1))) void*)(const_cast<u16*>(g)),
        (__attribute__((address_space(3))) void*)l, 16, 0, 0);
}

// ---------------- fused fp32 -> bf16 converts ----------------
__global__ __launch_bounds__(256) void cvt3_kernel(const float* __restrict__ a,
                                                   const float* __restrict__ b,
                                                   const float* __restrict__ c,
                                                   u16* __restrict__ da,
                                                   u16* __restrict__ db,
                                                   u16* __restrict__ dc) {
    const int i = blockIdx.x * 256 + threadIdx.x;       // 3 * 2^21 float4
    const int sel = i >> 21, off = i & ((1 << 21) - 1);
    const float* s = (sel == 0) ? a : (sel == 1) ? b : c;
    u16* d = (sel == 0) ? da : (sel == 1) ? db : dc;
    float4 v = ((const float4*)s)[off];
    ushort4 o;
    o.x = f2bf(v.x); o.y = f2bf(v.y); o.z = f2bf(v.z); o.w = f2bf(v.w);
    ((ushort4*)d)[off] = o;
}

__global__ __launch_bounds__(256) void cvt4_kernel(const float* __restrict__ a,
                                                   const float* __restrict__ b,
                                                   const float* __restrict__ c,
                                                   const float* __restrict__ d4,
                                                   u16* __restrict__ da,
                                                   u16* __restrict__ db,
                                                   u16* __restrict__ dc,
                                                   u16* __restrict__ dd) {
    const int i = blockIdx.x * 256 + threadIdx.x;       // 4 * 2^18 float4
    const int sel = i >> 18, off = i & ((1 << 18) - 1);
    const float* s = (sel == 0) ? a : (sel == 1) ? b : (sel == 2) ? c : d4;
    u16* d = (sel == 0) ? da : (sel == 1) ? db : (sel == 2) ? dc : dd;
    float4 v = ((const float4*)s)[off];
    ushort4 o;
    o.x = f2bf(v.x); o.y = f2bf(v.y); o.z = f2bf(v.z); o.w = f2bf(v.w);
    ((ushort4*)d)[off] = o;
}

// ---------------- fused QKV GEMM: C[M,1024] = A[M,1024] * W[1024,1024]^T ----------------
// which=0/1: bf16 row-major (Q/K). which=2: Vt[(b*NH+h)*DKK+d][s] via LDS transpose.
__global__ __launch_bounds__(256, 2) void gemm_qkv(const u16* __restrict__ XQ,
                                                   const u16* __restrict__ XK,
                                                   const u16* __restrict__ XV,
                                                   const u16* __restrict__ WQ,
                                                   const u16* __restrict__ WK,
                                                   const u16* __restrict__ WV,
                                                   u16* __restrict__ Qo,
                                                   u16* __restrict__ Ko,
                                                   u16* __restrict__ Vto) {
    constexpr int K = 1024, N = 1024;
    // smem: [ldsA 4096][ldsB 4096] during K-loop; reused as ldsT[128][136] in V-epilogue
    __shared__ __align__(16) u16 smem[17408];
    u16* ldsA = smem;
    u16* ldsB = smem + 4096;
    u16* ldsT = smem;

    const int which = blockIdx.x >> 9;       // 512 blocks per matmul
    const int inner = blockIdx.x & 511;
    const u16* A  = (which == 0) ? XQ : (which == 1) ? XK : XV;
    const u16* Bw = (which == 0) ? WQ : (which == 1) ? WK : WV;

    const int t = threadIdx.x;
    const int w = t >> 6, lane = t & 63;
    const int quad = lane >> 4, l15 = lane & 15;
    const int bn = inner & 7, bm = inner >> 3;
    const int wm = (w >> 1) * 64, wn = (w & 1) * 64;

    const u16* Ab = A  + (size_t)bm * 128 * K;
    const u16* Bb = Bw + (size_t)bn * 128 * K;
    const int srow  = lane >> 2;
    const int scol8 = (lane & 3) * 8;

    f32x4 acc[4][4];
    #pragma unroll
    for (int i = 0; i < 4; ++i)
        #pragma unroll
        for (int j = 0; j < 4; ++j)
            acc[i][j] = f32x4{0.f, 0.f, 0.f, 0.f};

    for (int k0 = 0; k0 < K; k0 += 32) {
        __syncthreads();
        #pragma unroll
        for (int i = 0; i < 2; ++i) {
            const int c = w * 2 + i;
            gl_lds16(Ab + (size_t)(c * 16 + srow) * K + k0 + scol8, &ldsA[c * 512]);
            gl_lds16(Bb + (size_t)(c * 16 + srow) * K + k0 + scol8, &ldsB[c * 512]);
        }
        __syncthreads();

        bf16x8 afr[4], bfr[4];
        #pragma unroll
        for (int i = 0; i < 4; ++i)
            afr[i] = *(const bf16x8*)&ldsA[(wm + i * 16 + l15) * 32 + quad * 8];
        #pragma unroll
        for (int j = 0; j < 4; ++j)
            bfr[j] = *(const bf16x8*)&ldsB[(wn + j * 16 + l15) * 32 + quad * 8];

        #pragma unroll
        for (int i = 0; i < 4; ++i)
            #pragma unroll
            for (int j = 0; j < 4; ++j)
                acc[i][j] = __builtin_amdgcn_mfma_f32_16x16x32_bf16(afr[i], bfr[j], acc[i][j], 0, 0, 0);
    }

    if (which < 2) {
        u16* outb = which ? Ko : Qo;
        #pragma unroll
        for (int i = 0; i < 4; ++i)
            #pragma unroll
            for (int j = 0; j < 4; ++j)
                #pragma unroll
                for (int r = 0; r < 4; ++r) {
                    const int row = bm * 128 + wm + i * 16 + quad * 4 + r;
                    const int col = bn * 128 + wn + j * 16 + l15;
                    outb[(size_t)row * N + col] = f2bf(acc[i][j][r]);
                }
    } else {
        // transpose 128x128 tile through LDS, then coalesced stores of Vt rows
        __syncthreads();   // everyone done reading ldsA/ldsB
        #pragma unroll
        for (int i = 0; i < 4; ++i)
            #pragma unroll
            for (int j = 0; j < 4; ++j)
                #pragma unroll
                for (int r = 0; r < 4; ++r) {
                    const int row_l = wm + i * 16 + quad * 4 + r;
                    const int col_l = wn + j * 16 + l15;
                    ldsT[col_l * 136 + row_l] = f2bf(acc[i][j][r]);
                }
        __syncthreads();
        const int c = t >> 1, half = t & 1;
        const int colg = bn * 128 + c;
        const int hh = colg >> 6, dd = colg & 63;
        const int bb = bm >> 4;                         // 16 bm-tiles per batch
        const int s0 = ((bm * 128) & 2047) + half * 64;
        const u16* srcl = ldsT + c * 136 + half * 64;
        u16* dstg = Vto + (size_t)((bb * NH + hh) * DKK + dd) * SEQ + s0;
        #pragma unroll
        for (int k = 0; k < 8; ++k)
            *(uint4*)(dstg + k * 8) = *(const uint4*)(srcl + k * 8);
    }
}

// ---------------- final projection GEMM: out[M,N] fp32 = A*W^T + bias ----------------
__global__ __launch_bounds__(256, 2) void gemm_proj(const u16* __restrict__ A,
                                                    const u16* __restrict__ Bw,
                                                    float* __restrict__ outf,
                                                    const float* __restrict__ bias) {
    constexpr int K = 1024, N = 1024;
    __shared__ __align__(16) u16 ldsA[128 * 32];
    __shared__ __align__(16) u16 ldsB[128 * 32];

    const int t = threadIdx.x;
    const int w = t >> 6, lane = t & 63;
    const int quad = lane >> 4, l15 = lane & 15;
    const int bn = blockIdx.x & 7, bm = blockIdx.x >> 3;
    const int wm = (w >> 1) * 64, wn = (w & 1) * 64;

    const u16* Ab = A  + (size_t)bm * 128 * K;
    const u16* Bb = Bw + (size_t)bn * 128 * K;
    const int srow  = lane >> 2;
    const int scol8 = (lane & 3) * 8;

    f32x4 acc[4][4];
    #pragma unroll
    for (int i = 0; i < 4; ++i)
        #pragma unroll
        for (int j = 0; j < 4; ++j)
            acc[i][j] = f32x4{0.f, 0.f, 0.f, 0.f};

    for (int k0 = 0; k0 < K; k0 += 32) {
        __syncthreads();
        #pragma unroll
        for (int i = 0; i < 2; ++i) {
            const int c = w * 2 + i;
            gl_lds16(Ab + (size_t)(c * 16 + srow) * K + k0 + scol8, &ldsA[c * 512]);
            gl_lds16(Bb + (size_t)(c * 16 + srow) * K + k0 + scol8, &ldsB[c * 512]);
        }
        __syncthreads();

        bf16x8 afr[4], bfr[4];
        #pragma unroll
        for (int i = 0; i < 4; ++i)
            afr[i] = *(const bf16x8*)&ldsA[(wm + i * 16 + l15) * 32 + quad * 8];
        #pragma unroll
        for (int j = 0; j < 4; ++j)
            bfr[j] = *(const bf16x8*)&ldsB[(wn + j * 16 + l15) * 32 + quad * 8];

        #pragma unroll
        for (int i = 0; i < 4; ++i)
            #pragma unroll
            for (int j = 0; j < 4; ++j)
                acc[i][j] = __builtin_amdgcn_mfma_f32_16x16x32_bf16(afr[i], bfr[j], acc[i][j], 0, 0, 0);
    }

    #pragma unroll
    for (int i = 0; i < 4; ++i)
        #pragma unroll
        for (int j = 0; j < 4; ++j)
            #pragma unroll
            for (int r = 0; r < 4; ++r) {
                const int row = bm * 128 + wm + i * 16 + quad * 4 + r;
                const int col = bn * 128 + wn + j * 16 + l15;
                outf[(size_t)row * N + col] = acc[i][j][r] + bias[col];
            }
}

// ---------------- causal flash attention v3 (S^T formulation) ----------------
// Grid 2048: bh = idx & 63 (XCD locality), qt = 31 - (idx>>6) (heavy blocks first).
// S^T = K*Q^T via mfma(kf, qf): lane holds S^T[s=kb+16jt+4quad+r][q=qw+l15] ->
// softmax row state (m,l,alpha) is PER-LANE (q=l15); P packs to 4 ds_write_b64
// with granule-XOR swizzle pos=(4jt+quad)^l15 (16 positions, ~conflict-free).
// O=P*V via mfma(pf, vf): output back in q=quad*4+r layout; alpha/l cross over
// via 4 ds_bpermutes.
__global__ __launch_bounds__(256, 4) void flash_attn(const u16* __restrict__ Qb,
                                                     const u16* __restrict__ Kb,
                                                     const u16* __restrict__ Vt,
                                                     u16* __restrict__ O) {
    __shared__ __align__(16) u16 ldsK[2 * 4096];   // [buf][d-chunk(2)][s 0..63][32 d] 16KB
    __shared__ __align__(16) u16 ldsV[2 * 4096];   // [buf][s-chunk(2)][d 0..63][32 s] 16KB
    __shared__ __align__(16) u16 ldsP[4 * 1024];   // per-wave [16 q][16 granules x 4] 8KB

    const int t = threadIdx.x;
    const int w = t >> 6, lane = t & 63;
    const int quad = lane >> 4, l15 = lane & 15;
    const int bh = blockIdx.x & 63;
    const int qt = 31 - (blockIdx.x >> 6);
    const int b = bh >> 4, h = bh & 15;
    const int q0 = qt * 64;
    const int qw = q0 + w * 16;

    const int srow  = lane >> 2;
    const int scol8 = (lane & 3) * 8;
    const size_t kbase = (size_t)b * SEQ * D_MODEL + h * DKK;
    const size_t vbase = (size_t)(bh * DKK) * SEQ;

    // Q B-frag (n=q on l15, k=d on quad*8+j)
    const u16* Qrow = Qb + (size_t)(b * SEQ + qw + l15) * D_MODEL + h * DKK;
    const bf16x8 qf0 = *(const bf16x8*)(Qrow + quad * 8);
    const bf16x8 qf1 = *(const bf16x8*)(Qrow + 32 + quad * 8);

    f32x4 o_acc[4];
    #pragma unroll
    for (int nt = 0; nt < 4; ++nt) o_acc[nt] = f32x4{0.f, 0.f, 0.f, 0.f};
    float m_i = -1e30f, l_i = 0.f;      // per-lane: q = qw + l15 (log2 domain)

    const float C2 = 0.18033688f;       // log2(e) / sqrt(dk)

    u16* PwS = &ldsP[w * 1024 + l15 * 64];

    // stage tile 0 into buffer 0
    {
        #pragma unroll
        for (int i = 0; i < 2; ++i) {
            const int e = w * 2 + i, ch = e >> 2, rb = (e & 3) * 16;
            gl_lds16(Kb + kbase + (size_t)(rb + srow) * D_MODEL + ch * 32 + scol8,
                     &ldsK[ch * 2048 + rb * 32]);
            gl_lds16(Vt + vbase + (size_t)(rb + srow) * SEQ + ch * 32 + scol8,
                     &ldsV[ch * 2048 + rb * 32]);
        }
    }

    int cur = 0;
    for (int it = 0; it <= qt; ++it) {
        const int kb = it * 64;
        __syncthreads();   // buf[cur] staged; prefetch below gets a full compute phase

        if (it < qt) {
            const int nb = (it + 1) * 64, nxt = cur ^ 1;
            #pragma unroll
            for (int i = 0; i < 2; ++i) {
                const int e = w * 2 + i, ch = e >> 2, rb = (e & 3) * 16;
                gl_lds16(Kb + kbase + (size_t)(nb + rb + srow) * D_MODEL + ch * 32 + scol8,
                         &ldsK[nxt * 4096 + ch * 2048 + rb * 32]);
                gl_lds16(Vt + vbase + (size_t)(rb + srow) * SEQ + nb + ch * 32 + scol8,
                         &ldsV[nxt * 4096 + ch * 2048 + rb * 32]);
            }
        }

        // ---- S^T = K Q^T: sc[jt] rows s=kb+16jt+4quad+r, cols q=qw+l15 ----
        f32x4 sc[4];
        #pragma unroll
        for (int jt = 0; jt < 4; ++jt) sc[jt] = f32x4{0.f, 0.f, 0.f, 0.f};
        #pragma unroll
        for (int ks = 0; ks < 2; ++ks) {
            const bf16x8 qf = ks ? qf1 : qf0;
            #pragma unroll
            for (int jt = 0; jt < 4; ++jt) {
                bf16x8 kf = *(const bf16x8*)&ldsK[cur * 4096 + ks * 2048 + (jt * 16 + l15) * 32 + quad * 8];
                sc[jt] = __builtin_amdgcn_mfma_f32_16x16x32_bf16(kf, qf, sc[jt], 0, 0, 0);
            }
        }

        // ---- causal mask: s > q (diag tile only; wave-uniform branch) ----
        if (kb + 63 > qw) {
            #pragma unroll
            for (int jt = 0; jt < 4; ++jt)
                #pragma unroll
                for (int r = 0; r < 4; ++r)
                    if (kb + jt * 16 + quad * 4 + r > qw + l15) sc[jt][r] = -3.0e38f;
        }

        // ---- row max: in-lane over 16 regs, then cross-quad ----
        float tmax = sc[0][0];
        #pragma unroll
        for (int jt = 0; jt < 4; ++jt)
            #pragma unroll
            for (int r = 0; r < 4; ++r) tmax = fmaxf(tmax, sc[jt][r]);
        tmax = fmaxf(tmax, __shfl_xor(tmax, 16));
        tmax = fmaxf(tmax, __shfl_xor(tmax, 32));

        const float mn = fmaxf(m_i, tmax * C2);
        const float alpha = fast_exp2(m_i - mn);
        m_i = mn;

        // ---- P = exp2(s*C2 - m); pack 4 bf16 per jt -> b64 write ----
        float tsum = 0.f;
        #pragma unroll
        for (int jt = 0; jt < 4; ++jt) {
            float p[4];
            #pragma unroll
            for (int r = 0; r < 4; ++r) {
                p[r] = fast_exp2(fmaf(sc[jt][r], C2, -mn));
                tsum += p[r];
            }
            const int pos = (4 * jt + quad) ^ l15;
            uint2 pk;
            pk.x = (uint32_t)f2bf(p[0]) | ((uint32_t)f2bf(p[1]) << 16);
            pk.y = (uint32_t)f2bf(p[2]) | ((uint32_t)f2bf(p[3]) << 16);
            *(uint2*)&PwS[pos * 4] = pk;
        }
        tsum += __shfl_xor(tsum, 16);
        tsum += __shfl_xor(tsum, 32);
        l_i = fmaf(l_i, alpha, tsum);

        // ---- alpha -> O layout (q = quad*4+r) via bpermute; rescale O ----
        float al[4];
        #pragma unroll
        for (int r = 0; r < 4; ++r)
            al[r] = __shfl(alpha, (lane & 48) | (quad * 4 + r));
        #pragma unroll
        for (int nt = 0; nt < 4; ++nt)
            #pragma unroll
            for (int r = 0; r < 4; ++r)
                o_acc[nt][r] *= al[r];

        asm volatile("s_waitcnt lgkmcnt(0)" ::: "memory");

        // ---- O += P V ----
        #pragma unroll
        for (int ks = 0; ks < 2; ++ks) {
            const int g = 8 * ks + 2 * quad;
            uint2 lo = *(const uint2*)&PwS[((g    ) ^ l15) * 4];
            uint2 hi = *(const uint2*)&PwS[((g + 1) ^ l15) * 4];
            union { bf16x8 v; uint2 u[2]; } pu;
            pu.u[0] = lo; pu.u[1] = hi;
            #pragma unroll
            for (int nt = 0; nt < 4; ++nt) {
                bf16x8 vf = *(const bf16x8*)&ldsV[cur * 4096 + ks * 2048 + (nt * 16 + l15) * 32 + quad * 8];
                o_acc[nt] = __builtin_amdgcn_mfma_f32_16x16x32_bf16(pu.v, vf, o_acc[nt], 0, 0, 0);
            }
        }

        cur ^= 1;
    }

    // epilogue: O[b, q, h*64+d] bf16; 1/l crosses layouts via bpermute
    const float rli = fast_rcp(l_i);
    float rl[4];
    #pragma unroll
    for (int r = 0; r < 4; ++r)
        rl[r] = __shfl(rli, (lane & 48) | (quad * 4 + r));
    #pragma unroll
    for (int nt = 0; nt < 4; ++nt)
        #pragma unroll
        for (int r = 0; r < 4; ++r) {
            const int qg = qw + quad * 4 + r;
            O[(size_t)(b * SEQ + qg) * D_MODEL + h * DKK + nt * 16 + l15] = f2bf(o_acc[nt][r] * rl[r]);
        }
}

// ---------------- host launch ----------------
extern "C" void kernel_launch(void* const* d_in, const int* in_sizes, int n_in,
                              void* d_out, int out_size, void* d_ws, size_t ws_size,
                              hipStream_t stream) {
    const float* q_in = (const float*)d_in[0];
    const float* k_in = (const float*)d_in[1];
    const float* v_in = (const float*)d_in[2];
    const float* Wq   = (const float*)d_in[3];
    const float* Wk   = (const float*)d_in[4];
    const float* Wv   = (const float*)d_in[5];
    const float* Wp   = (const float*)d_in[6];
    const float* bp   = (const float*)d_in[7];
    float* out = (float*)d_out;

    char* ws = (char*)d_ws;
    u16* XQ  = (u16*)(ws + (size_t)0);           // 16MB; reused as AttnOut
    u16* XK  = (u16*)(ws + ((size_t)16 << 20));
    u16* XV  = (u16*)(ws + ((size_t)32 << 20));
    u16* WQb = (u16*)(ws + ((size_t)48 << 20));
    u16* WKb = (u16*)(ws + ((size_t)50 << 20));
    u16* WVb = (u16*)(ws + ((size_t)52 << 20));
    u16* WPb = (u16*)(ws + ((size_t)54 << 20));
    u16* Qb  = (u16*)(ws + ((size_t)56 << 20));
    u16* Kb  = (u16*)(ws + ((size_t)72 << 20));
    u16* Vtb = (u16*)(ws + ((size_t)88 << 20));  // total 104 MB

    cvt3_kernel<<<3 * (1 << 21) / 256, 256, 0, stream>>>(q_in, k_in, v_in, XQ, XK, XV);
    cvt4_kernel<<<4 * (1 << 18) / 256, 256, 0, stream>>>(Wq, Wk, Wv, Wp, WQb, WKb, WVb, WPb);

    gemm_qkv<<<1536, 256, 0, stream>>>(XQ, XK, XV, WQb, WKb, WVb, Qb, Kb, Vtb);

    flash_attn<<<BATCH * NH * (SEQ / 64), 256, 0, stream>>>(Qb, Kb, Vtb, XQ);

    gemm_proj<<<512, 256, 0, stream>>>(XQ, WPb, out, bp);
}

// Round 4
// 305.642 us; speedup vs baseline: 1.6489x; 1.1380x over previous
//
#include <hip/hip_runtime.h>
#include <hip/hip_bf16.h>
#include <stdint.h>

// Problem constants (hard-coded: B=4, S=2048, D=1024, H=16, dk=64)
#define D_MODEL 1024
#define SEQ     2048
#define BATCH   4
#define NH      16
#define DKK     64
#define MROWS   (BATCH * SEQ)   // 8192

typedef unsigned short u16;
using bf16x8 = __attribute__((ext_vector_type(8))) __bf16;
using f32x4  = __attribute__((ext_vector_type(4))) float;

// float -> bf16 (RNE)
__device__ __forceinline__ u16 f2bf(float f) {
    union { float f; uint32_t u; } v; v.f = f;
    return (u16)((v.u + 0x7FFFu + ((v.u >> 16) & 1u)) >> 16);
}
// packed pair -> v_cvt_pk_bf16_f32 on gfx950
__device__ __forceinline__ uint32_t pk2bf(float a, float b) {
    union { __hip_bfloat162 h; uint32_t u; } v;
    v.h = __float22bfloat162_rn(float2{a, b});
    return v.u;
}

__device__ __forceinline__ float fast_exp2(float x) {
    float r; asm("v_exp_f32 %0, %1" : "=v"(r) : "v"(x)); return r;
}
__device__ __forceinline__ float fast_rcp(float x) {
    float r; asm("v_rcp_f32 %0, %1" : "=v"(r) : "v"(x)); return r;
}

// async global->LDS, 16B per lane; LDS dest wave-uniform base (+lane*16 implicit)
__device__ __forceinline__ void gl_lds16(const u16* g, u16* l) {
    __builtin_amdgcn_global_load_lds(
        (__attribute__((address_space(1))) void*)(const_cast<u16*>(g)),
        (__attribute__((address_space(3))) void*)l, 16, 0, 0);
}

// ---------------- fused fp32 -> bf16 converts ----------------
__global__ __launch_bounds__(256) void cvt3_kernel(const float* __restrict__ a,
                                                   const float* __restrict__ b,
                                                   const float* __restrict__ c,
                                                   u16* __restrict__ da,
                                                   u16* __restrict__ db,
                                                   u16* __restrict__ dc) {
    const int i = blockIdx.x * 256 + threadIdx.x;       // 3 * 2^21 float4
    const int sel = i >> 21, off = i & ((1 << 21) - 1);
    const float* s = (sel == 0) ? a : (sel == 1) ? b : c;
    u16* d = (sel == 0) ? da : (sel == 1) ? db : dc;
    float4 v = ((const float4*)s)[off];
    uint2 o;
    o.x = pk2bf(v.x, v.y); o.y = pk2bf(v.z, v.w);
    ((uint2*)d)[off] = o;
}

__global__ __launch_bounds__(256) void cvt4_kernel(const float* __restrict__ a,
                                                   const float* __restrict__ b,
                                                   const float* __restrict__ c,
                                                   const float* __restrict__ d4,
                                                   u16* __restrict__ da,
                                                   u16* __restrict__ db,
                                                   u16* __restrict__ dc,
                                                   u16* __restrict__ dd) {
    const int i = blockIdx.x * 256 + threadIdx.x;       // 4 * 2^18 float4
    const int sel = i >> 18, off = i & ((1 << 18) - 1);
    const float* s = (sel == 0) ? a : (sel == 1) ? b : (sel == 2) ? c : d4;
    u16* d = (sel == 0) ? da : (sel == 1) ? db : (sel == 2) ? dc : dd;
    float4 v = ((const float4*)s)[off];
    uint2 o;
    o.x = pk2bf(v.x, v.y); o.y = pk2bf(v.z, v.w);
    ((uint2*)d)[off] = o;
}

// ---------------- fused QKV GEMM: C[M,1024] = A[M,1024] * W[1024,1024]^T ----------------
// XCD-locality swizzle: x=inner&7 (XCD via %8 round-robin), bm=x*8+(j>>3), bn=j&7
// -> all 8 bn-blocks of a bm tile live on ONE XCD => A fetched once per XCD.
// Double-buffered LDS, single barrier per k-step.
// which=0/1: bf16 row-major (Q/K). which=2: Vt[(b*NH+h)*DKK+d][s] via LDS transpose.
__global__ __launch_bounds__(256, 3) void gemm_qkv(const u16* __restrict__ XQ,
                                                   const u16* __restrict__ XK,
                                                   const u16* __restrict__ XV,
                                                   const u16* __restrict__ WQ,
                                                   const u16* __restrict__ WK,
                                                   const u16* __restrict__ WV,
                                                   u16* __restrict__ Qo,
                                                   u16* __restrict__ Ko,
                                                   u16* __restrict__ Vto) {
    constexpr int K = 1024, N = 1024;
    // [ldsA 2x4096][ldsB 2x4096] in K-loop; reused as ldsT[128][136] in V-epilogue
    __shared__ __align__(16) u16 smem[17408];
    u16* ldsA = smem;               // [buf*4096 + ...]
    u16* ldsB = smem + 8192;
    u16* ldsT = smem;

    const int which = blockIdx.x >> 9;       // 512 blocks per matmul
    const int inner = blockIdx.x & 511;
    const u16* A  = (which == 0) ? XQ : (which == 1) ? XK : XV;
    const u16* Bw = (which == 0) ? WQ : (which == 1) ? WK : WV;

    const int t = threadIdx.x;
    const int w = t >> 6, lane = t & 63;
    const int quad = lane >> 4, l15 = lane & 15;
    const int x = inner & 7, j = inner >> 3;
    const int bm = x * 8 + (j >> 3), bn = j & 7;
    const int wm = (w >> 1) * 64, wn = (w & 1) * 64;

    const u16* Ab = A  + (size_t)bm * 128 * K;
    const u16* Bb = Bw + (size_t)bn * 128 * K;
    const int srow  = lane >> 2;
    const int scol8 = (lane & 3) * 8;

    f32x4 acc[4][4];
    #pragma unroll
    for (int i = 0; i < 4; ++i)
        #pragma unroll
        for (int jj = 0; jj < 4; ++jj)
            acc[i][jj] = f32x4{0.f, 0.f, 0.f, 0.f};

    // stage k=0 into buf 0
    #pragma unroll
    for (int i = 0; i < 2; ++i) {
        const int c = w * 2 + i;
        gl_lds16(Ab + (size_t)(c * 16 + srow) * K + scol8, &ldsA[c * 512]);
        gl_lds16(Bb + (size_t)(c * 16 + srow) * K + scol8, &ldsB[c * 512]);
    }

    int cur = 0;
    for (int k0 = 0; k0 < K; k0 += 32) {
        __syncthreads();   // buf[cur] staged (vmcnt drained); prev reads done
        if (k0 + 32 < K) {
            const int nxt = cur ^ 1;
            #pragma unroll
            for (int i = 0; i < 2; ++i) {
                const int c = w * 2 + i;
                gl_lds16(Ab + (size_t)(c * 16 + srow) * K + k0 + 32 + scol8, &ldsA[nxt * 4096 + c * 512]);
                gl_lds16(Bb + (size_t)(c * 16 + srow) * K + k0 + 32 + scol8, &ldsB[nxt * 4096 + c * 512]);
            }
        }

        bf16x8 afr[4], bfr[4];
        #pragma unroll
        for (int i = 0; i < 4; ++i)
            afr[i] = *(const bf16x8*)&ldsA[cur * 4096 + (wm + i * 16 + l15) * 32 + quad * 8];
        #pragma unroll
        for (int jj = 0; jj < 4; ++jj)
            bfr[jj] = *(const bf16x8*)&ldsB[cur * 4096 + (wn + jj * 16 + l15) * 32 + quad * 8];

        #pragma unroll
        for (int i = 0; i < 4; ++i)
            #pragma unroll
            for (int jj = 0; jj < 4; ++jj)
                acc[i][jj] = __builtin_amdgcn_mfma_f32_16x16x32_bf16(afr[i], bfr[jj], acc[i][jj], 0, 0, 0);
        cur ^= 1;
    }

    if (which < 2) {
        u16* outb = which ? Ko : Qo;
        #pragma unroll
        for (int i = 0; i < 4; ++i)
            #pragma unroll
            for (int jj = 0; jj < 4; ++jj)
                #pragma unroll
                for (int r = 0; r < 4; ++r) {
                    const int row = bm * 128 + wm + i * 16 + quad * 4 + r;
                    const int col = bn * 128 + wn + jj * 16 + l15;
                    outb[(size_t)row * N + col] = f2bf(acc[i][jj][r]);
                }
    } else {
        // transpose 128x128 tile through LDS, then coalesced Vt row stores
        __syncthreads();
        #pragma unroll
        for (int i = 0; i < 4; ++i)
            #pragma unroll
            for (int jj = 0; jj < 4; ++jj)
                #pragma unroll
                for (int r = 0; r < 4; ++r) {
                    const int row_l = wm + i * 16 + quad * 4 + r;
                    const int col_l = wn + jj * 16 + l15;
                    ldsT[col_l * 136 + row_l] = f2bf(acc[i][jj][r]);
                }
        __syncthreads();
        const int c = t >> 1, half = t & 1;
        const int colg = bn * 128 + c;
        const int hh = colg >> 6, dd = colg & 63;
        const int bb = bm >> 4;
        const int s0 = ((bm * 128) & 2047) + half * 64;
        const u16* srcl = ldsT + c * 136 + half * 64;
        u16* dstg = Vto + (size_t)((bb * NH + hh) * DKK + dd) * SEQ + s0;
        #pragma unroll
        for (int k = 0; k < 8; ++k)
            *(uint4*)(dstg + k * 8) = *(const uint4*)(srcl + k * 8);
    }
}

// ---------------- final projection GEMM: out[M,N] fp32 = A*W^T + bias ----------------
__global__ __launch_bounds__(256, 3) void gemm_proj(const u16* __restrict__ A,
                                                    const u16* __restrict__ Bw,
                                                    float* __restrict__ outf,
                                                    const float* __restrict__ bias) {
    constexpr int K = 1024, N = 1024;
    __shared__ __align__(16) u16 ldsA[2 * 4096];
    __shared__ __align__(16) u16 ldsB[2 * 4096];

    const int t = threadIdx.x;
    const int w = t >> 6, lane = t & 63;
    const int quad = lane >> 4, l15 = lane & 15;
    const int x = blockIdx.x & 7, j = blockIdx.x >> 3;
    const int bm = x * 8 + ((j & 63) >> 3), bn = j & 7;
    const int wm = (w >> 1) * 64, wn = (w & 1) * 64;

    const u16* Ab = A  + (size_t)bm * 128 * K;
    const u16* Bb = Bw + (size_t)bn * 128 * K;
    const int srow  = lane >> 2;
    const int scol8 = (lane & 3) * 8;

    f32x4 acc[4][4];
    #pragma unroll
    for (int i = 0; i < 4; ++i)
        #pragma unroll
        for (int jj = 0; jj < 4; ++jj)
            acc[i][jj] = f32x4{0.f, 0.f, 0.f, 0.f};

    #pragma unroll
    for (int i = 0; i < 2; ++i) {
        const int c = w * 2 + i;
        gl_lds16(Ab + (size_t)(c * 16 + srow) * K + scol8, &ldsA[c * 512]);
        gl_lds16(Bb + (size_t)(c * 16 + srow) * K + scol8, &ldsB[c * 512]);
    }

    int cur = 0;
    for (int k0 = 0; k0 < K; k0 += 32) {
        __syncthreads();
        if (k0 + 32 < K) {
            const int nxt = cur ^ 1;
            #pragma unroll
            for (int i = 0; i < 2; ++i) {
                const int c = w * 2 + i;
                gl_lds16(Ab + (size_t)(c * 16 + srow) * K + k0 + 32 + scol8, &ldsA[nxt * 4096 + c * 512]);
                gl_lds16(Bb + (size_t)(c * 16 + srow) * K + k0 + 32 + scol8, &ldsB[nxt * 4096 + c * 512]);
            }
        }

        bf16x8 afr[4], bfr[4];
        #pragma unroll
        for (int i = 0; i < 4; ++i)
            afr[i] = *(const bf16x8*)&ldsA[cur * 4096 + (wm + i * 16 + l15) * 32 + quad * 8];
        #pragma unroll
        for (int jj = 0; jj < 4; ++jj)
            bfr[jj] = *(const bf16x8*)&ldsB[cur * 4096 + (wn + jj * 16 + l15) * 32 + quad * 8];

        #pragma unroll
        for (int i = 0; i < 4; ++i)
            #pragma unroll
            for (int jj = 0; jj < 4; ++jj)
                acc[i][jj] = __builtin_amdgcn_mfma_f32_16x16x32_bf16(afr[i], bfr[jj], acc[i][jj], 0, 0, 0);
        cur ^= 1;
    }

    #pragma unroll
    for (int i = 0; i < 4; ++i)
        #pragma unroll
        for (int jj = 0; jj < 4; ++jj)
            #pragma unroll
            for (int r = 0; r < 4; ++r) {
                const int row = bm * 128 + wm + i * 16 + quad * 4 + r;
                const int col = bn * 128 + wn + jj * 16 + l15;
                outf[(size_t)row * N + col] = acc[i][jj][r] + bias[col];
            }
}

// ---------------- causal flash attention v4: 128-row Q blocks, 32 q/wave ----------------
// Grid 1024: bh = idx & 63 (XCD locality), qt = 15 - (idx>>6) (heavy first).
// Wave w owns q in [q0+32w, q0+32w+32) as TWO MFMA q-sets (g=0,1). K/V fragment
// reads are shared across both q-sets -> DS issue per MFMA halves vs v3.
// S^T = K Q^T (softmax per-lane, q=l15); per-wave skip of fully-masked tiles.
__global__ __launch_bounds__(256, 3) void flash_attn(const u16* __restrict__ Qb,
                                                     const u16* __restrict__ Kb,
                                                     const u16* __restrict__ Vt,
                                                     u16* __restrict__ O) {
    __shared__ __align__(16) u16 ldsK[2 * 4096];   // [buf][d-chunk(2)][s 0..63][32 d] 16KB
    __shared__ __align__(16) u16 ldsV[2 * 4096];   // [buf][s-chunk(2)][d 0..63][32 s] 16KB
    __shared__ __align__(16) u16 ldsP[4 * 2048];   // per-wave [2 qset][16 q][16 gran x 4] 16KB

    const int t = threadIdx.x;
    const int w = t >> 6, lane = t & 63;
    const int quad = lane >> 4, l15 = lane & 15;
    const int bh = blockIdx.x & 63;
    const int qt = 15 - (blockIdx.x >> 6);
    const int b = bh >> 4, h = bh & 15;
    const int q0 = qt * 128;
    const int qw = q0 + w * 32;

    const int srow  = lane >> 2;
    const int scol8 = (lane & 3) * 8;
    const size_t kbase = (size_t)b * SEQ * D_MODEL + h * DKK;
    const size_t vbase = (size_t)(bh * DKK) * SEQ;

    // Q B-frags (n=q on l15, k=d on quad*8+j), 2 q-sets x 2 k-halves
    bf16x8 qf[2][2];
    #pragma unroll
    for (int g = 0; g < 2; ++g) {
        const u16* Qrow = Qb + (size_t)(b * SEQ + qw + g * 16 + l15) * D_MODEL + h * DKK;
        qf[g][0] = *(const bf16x8*)(Qrow + quad * 8);
        qf[g][1] = *(const bf16x8*)(Qrow + 32 + quad * 8);
    }

    f32x4 o_acc[2][4];
    #pragma unroll
    for (int g = 0; g < 2; ++g)
        #pragma unroll
        for (int nt = 0; nt < 4; ++nt) o_acc[g][nt] = f32x4{0.f, 0.f, 0.f, 0.f};
    float m_i[2] = {-1e30f, -1e30f}, l_i[2] = {0.f, 0.f};

    const float C2 = 0.18033688f;   // log2(e) / sqrt(dk)
    u16* PwS = &ldsP[w * 2048];

    const int ntiles = 2 * qt + 2;

    // stage tile 0 into buffer 0
    #pragma unroll
    for (int i = 0; i < 2; ++i) {
        const int e = w * 2 + i, ch = e >> 2, rb = (e & 3) * 16;
        gl_lds16(Kb + kbase + (size_t)(rb + srow) * D_MODEL + ch * 32 + scol8,
                 &ldsK[ch * 2048 + rb * 32]);
        gl_lds16(Vt + vbase + (size_t)(rb + srow) * SEQ + ch * 32 + scol8,
                 &ldsV[ch * 2048 + rb * 32]);
    }

    int cur = 0;
    for (int it = 0; it < ntiles; ++it) {
        const int kb = it * 64;
        __syncthreads();   // buf[cur] staged; prefetch below gets full compute phase

        if (it + 1 < ntiles) {
            const int nb = kb + 64, nxt = cur ^ 1;
            #pragma unroll
            for (int i = 0; i < 2; ++i) {
                const int e = w * 2 + i, ch = e >> 2, rb = (e & 3) * 16;
                gl_lds16(Kb + kbase + (size_t)(nb + rb + srow) * D_MODEL + ch * 32 + scol8,
                         &ldsK[nxt * 4096 + ch * 2048 + rb * 32]);
                gl_lds16(Vt + vbase + (size_t)(rb + srow) * SEQ + nb + ch * 32 + scol8,
                         &ldsV[nxt * 4096 + ch * 2048 + rb * 32]);
            }
        }

        if (kb <= qw + 31) {   // wave-uniform: skip fully-masked tiles
            // ---- S^T = K Q^T for both q-sets; kf shared ----
            f32x4 sc[2][4];
            #pragma unroll
            for (int g = 0; g < 2; ++g)
                #pragma unroll
                for (int jt = 0; jt < 4; ++jt) sc[g][jt] = f32x4{0.f, 0.f, 0.f, 0.f};
            #pragma unroll
            for (int ks = 0; ks < 2; ++ks)
                #pragma unroll
                for (int jt = 0; jt < 4; ++jt) {
                    bf16x8 kf = *(const bf16x8*)&ldsK[cur * 4096 + ks * 2048 + (jt * 16 + l15) * 32 + quad * 8];
                    #pragma unroll
                    for (int g = 0; g < 2; ++g)
                        sc[g][jt] = __builtin_amdgcn_mfma_f32_16x16x32_bf16(kf, qf[g][ks], sc[g][jt], 0, 0, 0);
                }

            // ---- causal mask (diag region only) ----
            if (kb + 63 >= qw) {
                #pragma unroll
                for (int g = 0; g < 2; ++g)
                    #pragma unroll
                    for (int jt = 0; jt < 4; ++jt)
                        #pragma unroll
                        for (int r = 0; r < 4; ++r)
                            if (kb + jt * 16 + quad * 4 + r > qw + g * 16 + l15) sc[g][jt][r] = -3.0e38f;
            }

            // ---- softmax per q-set (per-lane rows) + P pack/store ----
            float alpha[2];
            #pragma unroll
            for (int g = 0; g < 2; ++g) {
                float tmax = sc[g][0][0];
                #pragma unroll
                for (int jt = 0; jt < 4; ++jt)
                    #pragma unroll
                    for (int r = 0; r < 4; ++r) tmax = fmaxf(tmax, sc[g][jt][r]);
                tmax = fmaxf(tmax, __shfl_xor(tmax, 16));
                tmax = fmaxf(tmax, __shfl_xor(tmax, 32));

                const float mn = fmaxf(m_i[g], tmax * C2);
                alpha[g] = fast_exp2(m_i[g] - mn);
                m_i[g] = mn;

                float tsum = 0.f;
                #pragma unroll
                for (int jt = 0; jt < 4; ++jt) {
                    float p[4];
                    #pragma unroll
                    for (int r = 0; r < 4; ++r) {
                        p[r] = fast_exp2(fmaf(sc[g][jt][r], C2, -mn));
                        tsum += p[r];
                    }
                    const int pos = (4 * jt + quad) ^ l15;
                    uint2 pk;
                    pk.x = pk2bf(p[0], p[1]);
                    pk.y = pk2bf(p[2], p[3]);
                    *(uint2*)&PwS[g * 1024 + l15 * 64 + pos * 4] = pk;
                }
                tsum += __shfl_xor(tsum, 16);
                tsum += __shfl_xor(tsum, 32);
                l_i[g] = fmaf(l_i[g], alpha[g], tsum);
            }

            // ---- alpha -> O layout (q = quad*4+r) via shfl; rescale O ----
            #pragma unroll
            for (int g = 0; g < 2; ++g) {
                float al[4];
                #pragma unroll
                for (int r = 0; r < 4; ++r)
                    al[r] = __shfl(alpha[g], (lane & 48) | (quad * 4 + r));
                #pragma unroll
                for (int nt = 0; nt < 4; ++nt)
                    #pragma unroll
                    for (int r = 0; r < 4; ++r)
                        o_acc[g][nt][r] *= al[r];
            }

            asm volatile("s_waitcnt lgkmcnt(0)" ::: "memory");

            // ---- O += P V ; vf shared across q-sets ----
            #pragma unroll
            for (int ks = 0; ks < 2; ++ks) {
                const int gg = 8 * ks + 2 * quad;
                union { bf16x8 v; uint2 u[2]; } pu[2];
                #pragma unroll
                for (int g = 0; g < 2; ++g) {
                    pu[g].u[0] = *(const uint2*)&PwS[g * 1024 + l15 * 64 + ((gg) ^ l15) * 4];
                    pu[g].u[1] = *(const uint2*)&PwS[g * 1024 + l15 * 64 + ((gg + 1) ^ l15) * 4];
                }
                #pragma unroll
                for (int nt = 0; nt < 4; ++nt) {
                    bf16x8 vf = *(const bf16x8*)&ldsV[cur * 4096 + ks * 2048 + (nt * 16 + l15) * 32 + quad * 8];
                    #pragma unroll
                    for (int g = 0; g < 2; ++g)
                        o_acc[g][nt] = __builtin_amdgcn_mfma_f32_16x16x32_bf16(pu[g].v, vf, o_acc[g][nt], 0, 0, 0);
                }
            }
        }

        cur ^= 1;
    }

    // epilogue: O[b, q, h*64+d] bf16; 1/l crosses layouts via shfl
    #pragma unroll
    for (int g = 0; g < 2; ++g) {
        const float rli = fast_rcp(l_i[g]);
        float rl[4];
        #pragma unroll
        for (int r = 0; r < 4; ++r)
            rl[r] = __shfl(rli, (lane & 48) | (quad * 4 + r));
        #pragma unroll
        for (int nt = 0; nt < 4; ++nt)
            #pragma unroll
            for (int r = 0; r < 4; ++r) {
                const int qg = qw + g * 16 + quad * 4 + r;
                O[(size_t)(b * SEQ + qg) * D_MODEL + h * DKK + nt * 16 + l15] = f2bf(o_acc[g][nt][r] * rl[r]);
            }
    }
}

// ---------------- host launch ----------------
extern "C" void kernel_launch(void* const* d_in, const int* in_sizes, int n_in,
                              void* d_out, int out_size, void* d_ws, size_t ws_size,
                              hipStream_t stream) {
    const float* q_in = (const float*)d_in[0];
    const float* k_in = (const float*)d_in[1];
    const float* v_in = (const float*)d_in[2];
    const float* Wq   = (const float*)d_in[3];
    const float* Wk   = (const float*)d_in[4];
    const float* Wv   = (const float*)d_in[5];
    const float* Wp   = (const float*)d_in[6];
    const float* bp   = (const float*)d_in[7];
    float* out = (float*)d_out;

    char* ws = (char*)d_ws;
    u16* XQ  = (u16*)(ws + (size_t)0);           // 16MB; reused as AttnOut
    u16* XK  = (u16*)(ws + ((size_t)16 << 20));
    u16* XV  = (u16*)(ws + ((size_t)32 << 20));
    u16* WQb = (u16*)(ws + ((size_t)48 << 20));
    u16* WKb = (u16*)(ws + ((size_t)50 << 20));
    u16* WVb = (u16*)(ws + ((size_t)52 << 20));
    u16* WPb = (u16*)(ws + ((size_t)54 << 20));
    u16* Qb  = (u16*)(ws + ((size_t)56 << 20));
    u16* Kb  = (u16*)(ws + ((size_t)72 << 20));
    u16* Vtb = (u16*)(ws + ((size_t)88 << 20));  // total 104 MB

    cvt3_kernel<<<3 * (1 << 21) / 256, 256, 0, stream>>>(q_in, k_in, v_in, XQ, XK, XV);
    cvt4_kernel<<<4 * (1 << 18) / 256, 256, 0, stream>>>(Wq, Wk, Wv, Wp, WQb, WKb, WVb, WPb);

    gemm_qkv<<<1536, 256, 0, stream>>>(XQ, XK, XV, WQb, WKb, WVb, Qb, Kb, Vtb);

    flash_attn<<<BATCH * NH * (SEQ / 128), 256, 0, stream>>>(Qb, Kb, Vtb, XQ);

    gemm_proj<<<512, 256, 0, stream>>>(XQ, WPb, out, bp);
}